// Round 12
// baseline (1994.817 us; speedup 1.0000x reference)
//
#include <hip/hip_runtime.h>
#include <hip/hip_bf16.h>
#include <cstdint>

#define B 2048
#define NL 32
#define FEAT 512
#define HID 512
#define HW 64
#define OUTSZ 42
#define G3 1536
#define LDIH 554   // gru_w_ih row stride
#define MB 16      // batch rows per block
#define NBLK (B/MB)   // 128
#define LDX 584    // lds_x row stride
#define LDH 520    // o1s row stride
#define CHW 16384  // bf16 elements per 32KB chunk

typedef __bf16 bf16x8 __attribute__((ext_vector_type(8)));
typedef unsigned short u16x8 __attribute__((ext_vector_type(8)));
typedef float f32x4 __attribute__((ext_vector_type(4)));
typedef __hip_bfloat16 bf16_t;

#define MFMA(a,b,c) __builtin_amdgcn_mfma_f32_16x16x32_bf16(a,b,c,0,0,0)

static __device__ __forceinline__ float sigmoidf_(float x){ return 1.f/(1.f+__expf(-x)); }

// ---------------- one-time weight prep into STAGING layouts ----------------
// (unchanged from the passing round-10 kernel)
// sA[54][512][32]: chunk (k0,g) at c=k0*3+g; row rp; granule gq holds
//   k-quarter half = gq ^ ((rp>>1)&3). sB[16][512][32]: lin1 chunks.
// sC[2][64][256]: lin2 k-halves, granule s holds g = s^(j&7).
// w_ssn[512][64]; w_ih512b, bias_comb: preamble GEMM.
__global__ __launch_bounds__(256) void prep4_kernel(
    const float* __restrict__ w_ih, const float* __restrict__ w_hh,
    const float* __restrict__ lin1_w, const float* __restrict__ lin2_w,
    const float* __restrict__ b_ih, const float* __restrict__ b_hh,
    bf16_t* __restrict__ sA, bf16_t* __restrict__ sB, bf16_t* __restrict__ sC,
    bf16_t* __restrict__ w_ssn, bf16_t* __restrict__ w_ih512b,
    float* __restrict__ bias_comb){
  const int NA = 54*CHW, NB2 = 16*CHW, NC2 = 2*CHW, NS = 512*64, NI = G3*512;
  const int total = NA+NB2+NC2+NS+NI+G3;
  for (int idx = blockIdx.x*256 + threadIdx.x; idx < total; idx += gridDim.x*256){
    int i = idx;
    if (i < NA){
      int c = i/CHW, r2 = i%CHW, rp = r2>>5, kk = r2&31, gq = kk>>3, e = kk&7;
      int k0 = c/3, g = c%3;
      int half = gq ^ ((rp>>1)&3);
      int orow = g*512 + rp;
      int k = k0*32 + half*8 + e;
      float v = (k < 512) ? w_hh[orow*512 + k]
              : ((k < 512+OUTSZ && g < 2) ? w_ih[(size_t)orow*LDIH + k] : 0.f);
      sA[i] = __float2bfloat16(v);
    } else if ((i -= NA) < NB2){
      int c = i/CHW, r2 = i%CHW, rp = r2>>5, kk = r2&31, gq = kk>>3, e = kk&7;
      int half = gq ^ ((rp>>1)&3);
      sB[i] = __float2bfloat16(lin1_w[rp*512 + c*32 + half*8 + e]);
    } else if ((i -= NB2) < NC2){
      int n = i/CHW, r2 = i%CHW, j = r2>>8, kk = r2&255, s = kk>>3, e = kk&7;
      int g = s ^ (j & 7);
      int k = n*256 + g*8 + e;
      float v = (j < OUTSZ) ? lin2_w[j*512 + k] : 0.f;
      sC[i] = __float2bfloat16(v);
    } else if ((i -= NC2) < NS){
      int j = i>>6, k = i&63;
      float v = (k < OUTSZ) ? w_ih[(size_t)(1024+j)*LDIH + 512 + k] : 0.f;
      w_ssn[i] = __float2bfloat16(v);
    } else if ((i -= NS) < NI){
      int r = i>>9, c = i&511;
      w_ih512b[i] = __float2bfloat16(w_ih[(size_t)r*LDIH + c]);
    } else {
      int j = i - NI;
      bias_comb[j] = b_ih[j] + (j < 1024 ? b_hh[j] : 0.f);
    }
  }
}

// ---------------- attention precompute (step-invariant) ----------------
__global__ __launch_bounds__(256) void att_kernel(const float* __restrict__ feat,
                                                  const float* __restrict__ att_w,
                                                  bf16_t* __restrict__ att_feat){
  int b = blockIdx.x;
  const float* fb = feat + (size_t)b * FEAT * HW;
  __shared__ float part[4][64];
  __shared__ float attv[64];
  int t = threadIdx.x;
  int s = t & 63, q = t >> 6;
  float acc = 0.f;
  for (int c = q*128; c < q*128 + 128; ++c)
    acc = fmaf(fb[c*HW + s], att_w[c], acc);
  part[q][s] = acc;
  __syncthreads();
  if (t < 64){
    float v = part[0][t] + part[1][t] + part[2][t] + part[3][t];
    float m = v;
    for (int o = 32; o > 0; o >>= 1) m = fmaxf(m, __shfl_xor(m, o));
    float e = __expf(v - m);
    float ssum = e;
    for (int o = 32; o > 0; o >>= 1) ssum += __shfl_xor(ssum, o);
    attv[t] = e / ssum * 2.0f;   // * BETA
  }
  __syncthreads();
  for (int c = t; c < FEAT; c += 256){
    const float4* row = (const float4*)(fb + c*HW);
    float a2 = 0.f;
    #pragma unroll
    for (int k = 0; k < 16; ++k){
      float4 v4 = row[k];
      a2 = fmaf(v4.x, attv[k*4+0], a2);
      a2 = fmaf(v4.y, attv[k*4+1], a2);
      a2 = fmaf(v4.z, attv[k*4+2], a2);
      a2 = fmaf(v4.w, attv[k*4+3], a2);
    }
    att_feat[(size_t)b*FEAT + c] = __float2bfloat16(a2);
  }
}

// ---------------- bf16 MFMA GEMM (NT) for gi_base preamble ----------------
__global__ __launch_bounds__(256) void gemm_mfma(const bf16_t* __restrict__ A,
                                                 const bf16_t* __restrict__ W,
                                                 const float* __restrict__ bias,
                                                 float* __restrict__ C,
                                                 int K, int lda, int ldw, int ldc){
  const int tid = threadIdx.x;
  const int w = tid >> 6, lane = tid & 63;
  const int r = lane & 15, half = lane >> 4;
  const int m_base = blockIdx.y * 64;
  const int n_base = blockIdx.x * 64 + w * 16;
  const bf16_t* Ap = A + (size_t)(m_base + r)*lda + half*8;
  const bf16_t* Wp = W + (size_t)(n_base + r)*ldw + half*8;
  f32x4 acc[4] = {};
  for (int k0 = 0; k0 < K; k0 += 32){
    bf16x8 bfrag = *(const bf16x8*)(Wp + k0);
    #pragma unroll
    for (int i = 0; i < 4; ++i){
      bf16x8 afrag = *(const bf16x8*)(Ap + (size_t)i*16*lda + k0);
      acc[i] = MFMA(afrag, bfrag, acc[i]);
    }
  }
  const float bv = bias ? bias[n_base + r] : 0.f;
  #pragma unroll
  for (int i = 0; i < 4; ++i)
    #pragma unroll
    for (int q = 0; q < 4; ++q)
      C[(size_t)(m_base + i*16 + half*4 + q)*ldc + n_base + r] = acc[i][q] + bv;
}

// ---------------- the 32-step scan: direct L2->VGPR weight stream ----------------
// 128 blocks x 512 threads (8 waves). Weights NEVER touch LDS: each wave runs a
// 6-buffer register pipeline (consume chunk c, reload buffer with chunk c+6).
// Reads of the staged layout are fully coalesced (64 lanes x 16B = 1KB/fragment).
// Only 4 barriers per step (A->gates->B->C). gi_base loaded per step in gates.
__global__ __launch_bounds__(512, 1) void mega9_kernel(
    const float* __restrict__ gi_base,
    const bf16_t* __restrict__ sA,
    const bf16_t* __restrict__ sB,
    const bf16_t* __restrict__ sC,
    const bf16_t* __restrict__ w_ssn,
    const float* __restrict__ lin1_b,
    const float* __restrict__ lin2_b,
    const float* __restrict__ b_hh,
    const float* __restrict__ gt,
    const int* __restrict__ line_prob,
    const float* __restrict__ sample_prob,
    float* __restrict__ out){
  __shared__ bf16_t lds_x[MB][LDX];      // [h(512) | ss(42) | zeros]
  __shared__ bf16_t o1s[MB][LDH];
  const int tid = threadIdx.x;
  const int wv = tid >> 6, l = tid & 63;
  const int lr = l & 15, half = l >> 4;
  const int m0 = blockIdx.x * MB;
  const int colbase = wv * 64;
  const int rowoff = (colbase + lr)*32 + (half ^ ((lr >> 1) & 3))*8;

  for (int i = tid; i < MB*LDX/2; i += 512) ((uint32_t*)lds_x)[i] = 0u;

  float bhn[4], lb1[4];
  #pragma unroll
  for (int ti = 0; ti < 4; ++ti){
    bhn[ti] = b_hh[1024 + colbase + ti*16 + lr];
    lb1[ti] = lin1_b[colbase + ti*16 + lr];
  }
  const int j3 = wv*16 + lr;
  const float b2c = (wv < 3 && j3 < OUTSZ) ? lin2_b[j3] : 0.f;
  // ssn weights persistent in VGPRs
  bf16x8 sfr[4][2];
  #pragma unroll
  for (int ti = 0; ti < 4; ++ti)
    #pragma unroll
    for (int ks = 0; ks < 2; ++ks)
      sfr[ti][ks] = *(const bf16x8*)(w_ssn + (size_t)(colbase + ti*16 + lr)*64 + ks*32 + half*8);

  float hp[4][4] = {};

  // chunk index -> staged base.  c in [0,54): A; [54,70): B; >=70: next step's A.
  auto wsrc = [&](int c)->const bf16_t*{
    if (c < 54) return sA + (size_t)c*CHW;
    if (c < 70) return sB + (size_t)(c-54)*CHW;
    return sA + (size_t)(c-70)*CHW;
  };

  // 6-buffer weight pipeline, all register-resident (static indices only)
  bf16x8 Wb[6][4];
  #pragma unroll
  for (int j = 0; j < 6; ++j){
    const bf16_t* s = wsrc(j) + rowoff;
    #pragma unroll
    for (int ti = 0; ti < 4; ++ti)
      Wb[j][ti] = *(const bf16x8*)(s + ti*512);
  }

  __syncthreads();

  #pragma unroll 1
  for (int t = 0; t < NL; ++t){
    // ========== phase A: ghss, 54 chunks, no barriers, reg pipeline ==========
    f32x4 accA[3][4] = {};
    #pragma unroll 1
    for (int k0 = 0; k0 < 18; k0 += 2){
      bf16x8 a0 = *(const bf16x8*)&lds_x[lr][k0*32 + half*8];
      bf16x8 a1 = *(const bf16x8*)&lds_x[lr][(k0+1)*32 + half*8];
      #pragma unroll
      for (int j = 0; j < 6; ++j){
        const int g = j % 3;
        bf16x8 a = (j < 3) ? a0 : a1;
        #pragma unroll
        for (int ti = 0; ti < 4; ++ti)
          accA[g][ti] = MFMA(a, Wb[j][ti], accA[g][ti]);
        const bf16_t* s = wsrc(3*k0 + 6 + j) + rowoff;   // reload 6 chunks ahead
        #pragma unroll
        for (int ti = 0; ti < 4; ++ti)
          Wb[j][ti] = *(const bf16x8*)(s + ti*512);
      }
    }

    // ---- ssn (weights in VGPRs; reads lds_x ss cols from prev step C) ----
    f32x4 accS[4] = {};
    #pragma unroll
    for (int ks = 0; ks < 2; ++ks){
      bf16x8 a2 = *(const bf16x8*)&lds_x[lr][512 + ks*32 + half*8];
      #pragma unroll
      for (int ti = 0; ti < 4; ++ti)
        accS[ti] = MFMA(a2, sfr[ti][ks], accS[ti]);
    }
    __syncthreads();   // (1) all lds_x reads done before gates rewrite h-cols

    // ---- gates: gi_base loaded per step (independent burst, single stall) ----
    #pragma unroll
    for (int ti = 0; ti < 4; ++ti)
      #pragma unroll
      for (int q = 0; q < 4; ++q){
        const float* gp = gi_base + (size_t)(m0 + half*4 + q)*G3 + colbase + ti*16 + lr;
        float ir = accA[0][ti][q] + gp[0];
        float iz = accA[1][ti][q] + gp[512];
        float hn = accA[2][ti][q] + bhn[ti];
        float gn = gp[1024] + accS[ti][q];
        float r = sigmoidf_(ir);
        float z = sigmoidf_(iz);
        float n = tanhf(gn + r*hn);
        float hv = (1.f - z)*n + z*hp[ti][q];
        hp[ti][q] = hv;
        lds_x[half*4 + q][colbase + ti*16 + lr] = __float2bfloat16(hv);
      }
    __syncthreads();   // (2) h ready for phase B

    // ========== phase B: lin1, 16 chunks, fully unrolled reg pipeline ==========
    f32x4 accB[4] = {};
    #pragma unroll
    for (int i = 0; i < 16; ++i){
      union { u16x8 u; bf16x8 b; } va;
      va.u = *(const u16x8*)&lds_x[lr][i*32 + half*8];
      #pragma unroll
      for (int e = 0; e < 8; ++e)
        if (va.u[e] & 0x8000) va.u[e] = 0;       // relu on bf16 sign
      #pragma unroll
      for (int ti = 0; ti < 4; ++ti)
        accB[ti] = MFMA(va.b, Wb[i % 6][ti], accB[ti]);
      // reload: chunks 60..69 continue B; i>=10 pre-positions next step's A
      // chunks so that buffer j holds chunk j on step entry (70%6 != 0 fix).
      const int rc = (i < 10) ? (60 + i) : (70 + ((i - 6) % 6));
      const bf16_t* s = wsrc(rc) + rowoff;
      #pragma unroll
      for (int ti = 0; ti < 4; ++ti)
        Wb[i % 6][ti] = *(const bf16x8*)(s + ti*512);
    }
    #pragma unroll
    for (int ti = 0; ti < 4; ++ti)
      #pragma unroll
      for (int q = 0; q < 4; ++q)
        o1s[half*4 + q][colbase + ti*16 + lr] =
            __float2bfloat16(fmaxf(accB[ti][q] + lb1[ti], 0.f));
    __syncthreads();   // (3) o1s ready

    // ========== phase C: lin2 (direct loads, waves 0..2) + outputs + ss ==========
    if (wv < 3){
      f32x4 accC = {};
      #pragma unroll
      for (int n = 0; n < 2; ++n)
        #pragma unroll
        for (int k0 = 0; k0 < 8; ++k0){
          bf16x8 a = *(const bf16x8*)&o1s[lr][(n*8 + k0)*32 + half*8];
          int sg = (k0*4 + half) ^ (j3 & 7);
          bf16x8 bf = *(const bf16x8*)(sC + (size_t)n*CHW + j3*256 + sg*8);
          accC = MFMA(a, bf, accC);
        }
      #pragma unroll
      for (int q = 0; q < 4; ++q){
        float val = accC[q] + b2c;
        int row = half*4 + q;
        int bm = m0 + row;
        if (j3 < 40){
          out[((size_t)bm*NL + t)*40 + j3] = val;
        } else if (j3 < 42){
          float other = __shfl_xor(val, 1);
          float mx = fmaxf(val, other);
          float e0 = __expf(val - mx), e1 = __expf(other - mx);
          out[(size_t)B*NL*40 + ((size_t)bm*NL + t)*2 + (j3 - 40)] = e0/(e0 + e1);
        }
        if (t + 1 < NL && j3 < OUTSZ){
          bool up = sample_prob[(size_t)(t+1)*B + bm] < 0.1f;
          float gtv;
          if (j3 < 40) gtv = gt[((size_t)bm*NL + t)*40 + j3];
          else {
            float pv = (float)line_prob[bm*NL + t];
            gtv = (j3 == 40) ? 1.f - pv : pv;
          }
          lds_x[row][512 + j3] = __float2bfloat16(up ? val : gtv);
        }
      }
    }
    __syncthreads();   // (4) ss ready for next step
  }
}

extern "C" void kernel_launch(void* const* d_in, const int* in_sizes, int n_in,
                              void* d_out, int out_size, void* d_ws, size_t ws_size,
                              hipStream_t stream) {
  const float* img         = (const float*)d_in[0];
  const float* gt          = (const float*)d_in[1];
  const int*   line_prob   = (const int*)d_in[2];
  const float* sample_prob = (const float*)d_in[3];
  const float* att_w       = (const float*)d_in[4];
  // d_in[5] att_b: unused — softmax shift-invariance cancels it
  const float* w_ih        = (const float*)d_in[6];
  const float* w_hh        = (const float*)d_in[7];
  const float* b_ih        = (const float*)d_in[8];
  const float* b_hh        = (const float*)d_in[9];
  const float* lin1_w      = (const float*)d_in[10];
  const float* lin1_b      = (const float*)d_in[11];
  const float* lin2_w      = (const float*)d_in[12];
  const float* lin2_b      = (const float*)d_in[13];
  float* out = (float*)d_out;

  char* p = (char*)d_ws;
  auto alloc = [&](size_t bytes){ void* q = p; p += (bytes + 255) & ~(size_t)255; return q; };
  float*  gi_base   = (float*)alloc((size_t)B*G3*4);
  bf16_t* att_bf    = (bf16_t*)alloc((size_t)B*FEAT*2);
  bf16_t* sA        = (bf16_t*)alloc((size_t)54*CHW*2);
  bf16_t* sB        = (bf16_t*)alloc((size_t)16*CHW*2);
  bf16_t* sC        = (bf16_t*)alloc((size_t)2*CHW*2);
  bf16_t* w_ssn     = (bf16_t*)alloc((size_t)512*64*2);
  bf16_t* w_ih512b  = (bf16_t*)alloc((size_t)G3*512*2);
  float*  bias_comb = (float*)alloc((size_t)G3*4);

  prep4_kernel<<<4096, 256, 0, stream>>>(w_ih, w_hh, lin1_w, lin2_w, b_ih, b_hh,
                                         sA, sB, sC, w_ssn, w_ih512b, bias_comb);
  att_kernel<<<B, 256, 0, stream>>>(img, att_w, att_bf);
  gemm_mfma<<<dim3(G3/64, B/64), 256, 0, stream>>>(att_bf, w_ih512b, bias_comb, gi_base,
                                                   512, 512, 512, G3);
  mega9_kernel<<<NBLK, 512, 0, stream>>>(gi_base, sA, sB, sC, w_ssn, lin1_b, lin2_b,
                                         b_hh, gt, line_prob, sample_prob, out);
}